// Round 14
// baseline (331.296 us; speedup 1.0000x reference)
//
#include <hip/hip_runtime.h>
#include <hip/hip_bf16.h>
#include <stdint.h>

#define B_ 128
#define N_ 512
#define S_ 8
#define H_ 64
#define M_ (B_*N_)          // 65536 rows
#define L2E 1.442695041f

// wg layout (shorts): 7 matrices x 4096 | Whh frags 16384 | Wxc 1024
#define WHH_OFF 28672
#define WXC_OFF 45056

typedef __attribute__((ext_vector_type(8))) short bf16x8;
typedef __attribute__((ext_vector_type(4))) float f32x4;

__device__ __forceinline__ float exp2f_(float x) { return __builtin_amdgcn_exp2f(x); }
__device__ __forceinline__ float rcpf_(float x)  { return __builtin_amdgcn_rcpf(x); }
// x pre-scaled by log2(e):  sig2(x) == sigmoid(x / L2E)   (v_exp + v_rcp only)
__device__ __forceinline__ float sig2(float x)  { return rcpf_(1.f + exp2f_(-x)); }
// x pre-scaled by 2*log2(e): tanh2(x) == tanh(x / (2*L2E))
__device__ __forceinline__ float tanh2(float x) { return 1.f - 2.f*rcpf_(exp2f_(x) + 1.f); }
// fp32 -> bf16 round-to-nearest-even
__device__ __forceinline__ unsigned short f2bf(float x) {
  unsigned int u = __float_as_uint(x);
  u += 0x7fffu + ((u >> 16) & 1u);
  return (unsigned short)(u >> 16);
}

// ---------------------------------------------------------------------------
// One-shot weight conversion, 12 blocks x 512 threads (~4 us). Unchanged.
__global__ __launch_bounds__(512) void wconv_kernel(
    const float* __restrict__ W1, const float* __restrict__ W2,
    const float* __restrict__ Wh, const float* __restrict__ Wq,
    const float* __restrict__ Wk, const float* __restrict__ Wv,
    const float* __restrict__ Wf, const float* __restrict__ Wih,
    const float* __restrict__ Whh, const float* __restrict__ bih,
    const float* __restrict__ bhh, unsigned short* __restrict__ wg)
{
  const int m = blockIdx.x;
  const int tid = threadIdx.x;
  if (m < 6) {
    const int f = tid >> 6, l = tid & 63;
    const int lq = l >> 4, lc = l & 15;
    const float* mats[6] = {W1, W2, Wh, Wq, Wk, Wv};
    const float sc = (m == 3) ? L2E : 1.f;       // Wq pre-scaled by log2(e)
    const int nt = f >> 1, s = f & 1;
    const float* src = mats[m] + (size_t)(nt*16 + lc)*64 + s*32 + lq*8;
    bf16x8 v;
    #pragma unroll
    for (int j = 0; j < 8; ++j) v[j] = (short)f2bf(src[j] * sc);
    *(bf16x8*)(wg + (size_t)m*4096 + f*512 + l*8) = v;
  } else if (m == 6) {
    const int f = tid >> 6, l = tid & 63;
    const int lq = l >> 4, lc = l & 15;
    const int kc = f >> 1, nt = f & 1;
    const int n = nt*16 + lc;
    bf16x8 v;
    #pragma unroll
    for (int j = 0; j < 8; ++j) v[j] = 0;
    if (n < 24) {
      const float* src = Wf + (size_t)n*128 + kc*32 + lq*8;
      #pragma unroll
      for (int j = 0; j < 8; ++j) v[j] = (short)f2bf(src[j]);
    }
    *(bf16x8*)(wg + (size_t)6*4096 + f*512 + l*8) = v;
  } else if (m < 11) {
    // Whh gate-scaled B-frags
    const int p = (m - 7)*512 + tid;             // 0..2047
    const int f = p >> 6, l = p & 63;
    const int t16 = f >> 1, s = f & 1;
    const int lq = l >> 4, lc = l & 15;
    const float sc = (t16 >= 8 && t16 < 12) ? (2.f*L2E) : L2E;
    const float* src = Whh + (size_t)(t16*16 + lc)*64 + s*32 + lq*8;
    bf16x8 v;
    #pragma unroll
    for (int j = 0; j < 8; ++j) v[j] = (short)f2bf(src[j] * sc);
    *(bf16x8*)(wg + WHH_OFF + (size_t)p*8) = v;
  } else {
    // compact Wx: [t16*64 + cc*4 + k], k: 0=Wih0 1=Wih1 2=bias 3=0
    if (tid < 256) {
      const int t16 = tid >> 4, cc = tid & 15;
      const int n = t16*16 + cc;
      const float sc = (t16 >= 8 && t16 < 12) ? (2.f*L2E) : L2E;
      unsigned short* d = wg + WXC_OFF + t16*64 + cc*4;
      d[0] = f2bf(Wih[2*n + 0] * sc);
      d[1] = f2bf(Wih[2*n + 1] * sc);
      d[2] = f2bf((bih[n] + bhh[n]) * sc);
      d[3] = 0;
    }
  }
}

// ---------------------------------------------------------------------------
// FUSED LSTM+MLP v15 = v14 with a WAVE-PAIR cc-SPLIT for +50% occupancy.
//  - 512 threads = 8 waves = 4 pairs; each pair owns 16 rows (64 rows/block,
//    grid 1024). Both waves of a pair build IDENTICAL A-frags; half 0
//    computes gate-tile cols cc{0,1} (h cols 0..31), half 1 cc{2,3}
//    (cols 32..63). MFMA total unchanged; VALU/wave halved; 8192 waves.
//  - One __syncthreads per t-step (h halves must be visible for the next
//    step's A-frag read; the t=7 barrier doubles as the pre-MLP sync).
//  - LDS 44032 B (Wfrag 32K + Wxc 2K + h_s 64x72) -> 3 blocks/CU = 24
//    waves/CU (was 16). Grid 1024 = 3 resident + rotation (no tail).
//  - pm strips halve: 128 words/wave, 2 int4 loads/step (same bit layout).
//  - MLP epilogue unchanged, run by half==0 waves on their pair's 16 rows
//    (disjoint h_s slices; epilogue has no barriers -> no divergence hazard).
//  - Per-cell math/order bit-identical to v14.
__global__ __launch_bounds__(512, 6) void lstm_kernel(
    const float* __restrict__ obs, const float* __restrict__ nhm,
    const int4* __restrict__ pm4, uint32_t* __restrict__ bm,
    const unsigned short* __restrict__ wg,
    const float* __restrict__ b1, const float* __restrict__ b2,
    const float* __restrict__ bh, const float* __restrict__ bq,
    const float* __restrict__ bk, const float* __restrict__ bv,
    unsigned short* __restrict__ qb, unsigned short* __restrict__ kb,
    unsigned short* __restrict__ vt, float* __restrict__ feat)
{
  __shared__ short    Wfrag[32*512];   // 32 KB  Whh B-frags (bf16, gate-scaled)
  __shared__ short    Wxc[1024];       // 2 KB   compact [Wih0,Wih1,bias,0] per n
  __shared__ short    h_s[64*72];      // 9 KB   bf16, stride 72 (reused as Atile)

  const int tid  = threadIdx.x;
  const int lane = tid & 63;
  const int wv   = tid >> 6;           // 0..7
  const int pr   = wv >> 1;            // pair 0..3
  const int half = wv & 1;             // 0: cc{0,1}, 1: cc{2,3}
  const int w16  = pr * 16;
  const int quad = lane >> 4;
  const int col  = lane & 15;
  const int row0 = blockIdx.x * 64;

  // pm strip for this wave: 128 words = 1024 int4
  const int     wb  = (blockIdx.x*8 + wv) * 128;       // word base
  const int4*   pw  = pm4 + (size_t)wb * 8;            // int4 base
  const int     shp = (lane & 7) * 4;                  // nibble shift

  // ---- prologue: coalesced copies from pre-converted wg ----
  #pragma unroll
  for (int i = 0; i < 4; ++i) {
    int p = i*512 + tid;               // (f*64+l) entry index; dst off = p*8
    *(bf16x8*)(Wfrag + (size_t)p*8) =
        *(const bf16x8*)(wg + WHH_OFF + (size_t)p*8);
  }
  ((uint32_t*)Wxc)[tid] = ((const uint32_t*)(wg + WXC_OFF))[tid];

  // zero h_s (2304 dwords)
  #pragma unroll
  for (int i = 0; i < 5; ++i) {
    int idx = i*512 + tid;
    if (idx < 2304) ((uint32_t*)h_s)[idx] = 0u;
  }

  // ---- per-lane x prep for row (w16+col); both halves redundant, so each
  //      consumer lane already holds its own value. Registers, no LDS.
  uint32_t xq0, xq1, xq2, xq3, xq4, xq5, xq6, xq7;
  int len;
  {
    const int grow = row0 + w16 + col;
    float xv0[8], xv1[8];
    int lzi = -1;
    #pragma unroll
    for (int t = 0; t < 8; ++t) {
      float m = nhm[(size_t)grow*8 + t];
      float a = obs[((size_t)grow*8 + t)*2 + 0] * m;
      float b = obs[((size_t)grow*8 + t)*2 + 1] * m;
      xv0[t] = a; xv1[t] = b;
      if (a == 0.f) lzi = t;
    }
    uint32_t xr[8];
    #pragma unroll
    for (int t = 0; t < 8; ++t) {
      bool kill = (t < lzi);
      float a = kill ? 0.f : xv0[t];
      float b = kill ? 0.f : xv1[t];
      xr[t] = (uint32_t)f2bf(a) | ((uint32_t)f2bf(b) << 16);
    }
    xq0 = xr[0]; xq1 = xr[1]; xq2 = xr[2]; xq3 = xr[3];
    xq4 = xr[4]; xq5 = xr[5]; xq6 = xr[6]; xq7 = xr[7];
    len = 7 - lzi; if (len < 1) len = 1;
  }
  int lenr[4];
  #pragma unroll
  for (int r = 0; r < 4; ++r) lenr[r] = __shfl(len, quad*4 + r);

  __syncthreads();     // covers Wfrag, Wxc, h_s zero

  float c_[8];
  #pragma unroll
  for (int i = 0; i < 8; ++i) c_[i] = 0.f;

  const f32x4 zero4 = {0.f, 0.f, 0.f, 0.f};
  const bool q0 = (quad == 0);

  #pragma unroll 1
  for (int t = 0; t < 8; ++t) {
    // ---- ISSUE pm loads for this step early (consumed after cc-loop) ----
    const int4* ps = pw + t*128 + lane;
    int4 pv0 = ps[0];
    int4 pv1 = ps[64];
    __builtin_amdgcn_sched_barrier(0);   // loads stay issued before MFMA region

    // ---- A-frag for the x/bias MFMA: [x0, x1, 1, 0...] on quad 0 ----
    uint32_t xw = xq0;
    // rotate queue (static indices; stays in registers)
    xq0 = xq1; xq1 = xq2; xq2 = xq3; xq3 = xq4;
    xq4 = xq5; xq5 = xq6; xq6 = xq7;

    union { bf16x8 v; uint32_t u[4]; } ax;
    ax.u[0] = q0 ? xw : 0u;
    ax.u[1] = q0 ? 0x00003f80u : 0u;    // bf16(1.0) at k==2
    ax.u[2] = 0u; ax.u[3] = 0u;

    // A-frags of h (bf16, no converts) — identical in both halves
    bf16x8 a0 = *(const bf16x8*)(h_s + (w16 + col)*72 + quad*8);
    bf16x8 a1 = *(const bf16x8*)(h_s + (w16 + col)*72 + 32 + quad*8);

    // this wave's 2 column-groups: cc = half*2 + cci; tiles {cc,cc+4,cc+8,cc+12}
    #pragma unroll
    for (int cci = 0; cci < 2; ++cci) {
      const int cca = half*2 + cci;
      f32x4 acc[4];
      #pragma unroll
      for (int g = 0; g < 4; ++g) {
        const int t16 = g*4 + cca;
        union { bf16x8 v; uint32_t u[4]; } wx;
        uint2 d = *(const uint2*)(Wxc + t16*64 + col*4);  // always initialized
        wx.u[0] = q0 ? d.x : 0u;        // zero fragment on non-quad0 lanes
        wx.u[1] = q0 ? d.y : 0u;
        wx.u[2] = 0u; wx.u[3] = 0u;
        bf16x8 b0 = *(const bf16x8*)(Wfrag + (t16*2+0)*512 + lane*8);
        bf16x8 b1 = *(const bf16x8*)(Wfrag + (t16*2+1)*512 + lane*8);
        acc[g] = __builtin_amdgcn_mfma_f32_16x16x32_bf16(ax.v, wx.v, zero4, 0, 0, 0);
        acc[g] = __builtin_amdgcn_mfma_f32_16x16x32_bf16(a0, b0, acc[g], 0, 0, 0);
        acc[g] = __builtin_amdgcn_mfma_f32_16x16x32_bf16(a1, b1, acc[g], 0, 0, 0);
      }
      #pragma unroll
      for (int r = 0; r < 4; ++r) {
        if (t < lenr[r]) {
          float gi = acc[0][r];
          float gf = acc[1][r];
          float gg = acc[2][r];
          float go = acc[3][r];
          float cn = sig2(gf)*c_[cci*4+r] + sig2(gi)*tanh2(gg);
          c_[cci*4+r] = cn;
          h_s[(w16 + quad*4 + r)*72 + cca*16 + col] =
              (short)f2bf(sig2(go)*tanh2(cn*(2.f*L2E)));
        }
      }
      __builtin_amdgcn_sched_barrier(0);  // pin group: keep acc lifetime short
    }

    // ---- CONSUME pm loads (latency hidden under the cc-loop above) ----
    {
      int4 vv[2] = {pv0, pv1};
      #pragma unroll
      for (int jj = 0; jj < 2; ++jj) {
        int4 v = vv[jj];
        uint32_t nib = (v.x != 0 ? 1u : 0u)
                     | (v.y != 0 ? 2u : 0u)
                     | (v.z != 0 ? 4u : 0u)
                     | (v.w != 0 ? 8u : 0u);
        uint32_t x = nib << shp;
        x |= __shfl_xor(x, 1);
        x |= __shfl_xor(x, 2);
        x |= __shfl_xor(x, 4);
        if ((lane & 7) == 0)
          bm[wb + t*16 + jj*8 + (lane >> 3)] = x;
      }
      __builtin_amdgcn_sched_barrier(0);
    }

    __syncthreads();   // pair halves exchange h columns for next step / MLP
  }

  // ======================= fused MLP epilogue (half==0 waves) ==============
  if (half == 0) {
    short* At = h_s + w16*72;          // this pair's 16-row slice, stride 72
    const int grow16 = row0 + w16;     // row base for this pair

    auto reluv = [](bf16x8 v) {
      #pragma unroll
      for (int j = 0; j < 8; ++j) {
        short sv = v[j];
        v[j] = (sv & (short)0x8000) ? (short)0 : sv;
      }
      return v;
    };

    bf16x8 a0 = reluv(*(const bf16x8*)(At + col*72 + quad*8));
    bf16x8 a1 = reluv(*(const bf16x8*)(At + col*72 + 32 + quad*8));

    f32x4 acc[4];
    auto runL = [&](int m, const float* __restrict__ bs, float bsc) {
      bf16x8 bf[8];
      #pragma unroll
      for (int f = 0; f < 8; ++f)
        bf[f] = *(const bf16x8*)(wg + (size_t)m*4096 + f*512 + lane*8);
      #pragma unroll
      for (int nt = 0; nt < 4; ++nt) {
        float bb = bs[nt*16 + col] * bsc;
        acc[nt][0] = bb; acc[nt][1] = bb; acc[nt][2] = bb; acc[nt][3] = bb;
        acc[nt] = __builtin_amdgcn_mfma_f32_16x16x32_bf16(a0, bf[nt*2+0], acc[nt], 0,0,0);
        acc[nt] = __builtin_amdgcn_mfma_f32_16x16x32_bf16(a1, bf[nt*2+1], acc[nt], 0,0,0);
      }
    };
    auto tileWrite = [&](bool relu) {
      #pragma unroll
      for (int nt = 0; nt < 4; ++nt)
        #pragma unroll
        for (int r = 0; r < 4; ++r) {
          float v = relu ? fmaxf(acc[nt][r], 0.f) : acc[nt][r];
          At[(quad*4+r)*72 + ((nt*16+col) ^ (r*16))] = (short)f2bf(v);
        }
    };
    auto tileReadA = [&]() {
      int sw = (col & 3) * 16;
      a0 = *(const bf16x8*)(At + col*72 + ((quad*8     ) ^ sw));
      a1 = *(const bf16x8*)(At + col*72 + ((quad*8 + 32) ^ sw));
    };
    auto storeBF = [&](unsigned short* dst) {
      #pragma unroll
      for (int s = 0; s < 2; ++s) {
        int chunk = s*64 + lane;
        int r = chunk >> 3, c8 = chunk & 7;
        bf16x8 v = *(const bf16x8*)(At + r*72 + ((c8*8) ^ ((r&3)*16)));
        *(bf16x8*)(dst + (size_t)(grow16 + r)*64 + c8*8) = v;
      }
    };

    runL(0, b1, 1.f);  tileWrite(true);  tileReadA();
    runL(1, b2, 1.f);  tileWrite(true);  tileReadA();
    runL(2, bh, 1.f);  tileWrite(true);  tileReadA();   // a0/a1 = hidden A-frags
    runL(3, bq, L2E);  tileWrite(false); storeBF(qb);   // q (bf16, L2E-scaled)
    runL(4, bk, 1.f);  tileWrite(false); storeBF(kb);   // k (bf16)
    runL(5, bv, 1.f);                                   // v
    {
      const int bi   = grow16 >> 9;                // batch
      const int key0 = (grow16 & 511) + quad*4;
      #pragma unroll
      for (int nt = 0; nt < 4; ++nt) {
        #pragma unroll
        for (int r = 0; r < 4; ++r)
          feat[(size_t)(grow16 + quad*4 + r)*128 + nt*16 + col] = acc[nt][r];
        uint32_t lo = (uint32_t)f2bf(acc[nt][0]) | ((uint32_t)f2bf(acc[nt][1]) << 16);
        uint32_t hi = (uint32_t)f2bf(acc[nt][2]) | ((uint32_t)f2bf(acc[nt][3]) << 16);
        uint2 pk; pk.x = lo; pk.y = hi;
        *(uint2*)(vt + ((size_t)bi*64 + nt*16 + col)*512 + key0) = pk;
      }
    }
  }
}

// ---------------------------------------------------------------------------
// MFMA attention v4 (unchanged): fused forecast epilogue, Wf frags from wg.
__global__ __launch_bounds__(256) void attn_kernel(
    const unsigned short* __restrict__ qg, const unsigned short* __restrict__ kg,
    const unsigned short* __restrict__ vt,
    const uint32_t* __restrict__ bm, float* __restrict__ feat,
    const unsigned short* __restrict__ wg, const float* __restrict__ bfv,
    float* __restrict__ out)
{
  __shared__ short    Ks[128*72];      // 18.0 KB (reused as o-tile in epilogue)
  __shared__ short    Vt[64*136];      // 17.0 KB
  __shared__ short    Pl[4][16*32];    // 4 KB, per-wave
  __shared__ uint32_t Ms[4][256];      // 4 KB, per-wave mask words

  const int tid  = threadIdx.x;
  const int lane = tid & 63;
  const int wv   = tid >> 6;
  const int w16  = wv * 16;
  const int quad = lane >> 4;
  const int col  = lane & 15;

  const int b     = blockIdx.x >> 3;
  const int q0    = (blockIdx.x & 7) * 64;
  const int qbase = b*512 + q0 + wv*16;

  bf16x8 qa[2];
  qa[0] = *(const bf16x8*)(qg + (size_t)(qbase + col)*64 + quad*8);
  qa[1] = *(const bf16x8*)(qg + (size_t)(qbase + col)*64 + quad*8 + 32);

  #pragma unroll
  for (int w = 0; w < 4; ++w)
    Ms[wv][w*64 + lane] = bm[(size_t)qbase*16 + w*64 + lane];

  f32x4 o_acc[4];
  #pragma unroll
  for (int nt = 0; nt < 4; ++nt)
    #pragma unroll
    for (int r = 0; r < 4; ++r) o_acc[nt][r] = 0.f;
  float l_part[4] = {0.f, 0.f, 0.f, 0.f};

  const unsigned short* vtb = vt + (size_t)b*64*512;

  for (int c = 0; c < 4; ++c) {
    __syncthreads();
    {
      const int kb_ = b*512 + c*128;
      // K chunk: bf16 [key][dim] stride 72
      #pragma unroll
      for (int i = 0; i < 4; ++i) {
        int p = i*256 + tid;
        int key = p >> 3, c8 = p & 7;
        bf16x8 kv = *(const bf16x8*)(kg + (size_t)(kb_ + key)*64 + c8*8);
        *(bf16x8*)(Ks + key*72 + c8*8) = kv;
      }
      // V^T chunk: bf16 [dim][key] stride 136 — pure copies
      #pragma unroll
      for (int i = 0; i < 4; ++i) {
        int p = i*256 + tid;
        int dim = p >> 4, k8 = p & 15;
        bf16x8 vv = *(const bf16x8*)(vtb + (size_t)dim*512 + c*128 + k8*8);
        *(bf16x8*)(Vt + dim*136 + k8*8) = vv;
      }
    }
    __syncthreads();

    for (int kc = 0; kc < 4; ++kc) {
      #pragma unroll
      for (int t = 0; t < 2; ++t) {
        const int kt = kc*2 + t;
        f32x4 s_acc;
        #pragma unroll
        for (int r = 0; r < 4; ++r) s_acc[r] = 0.f;
        const short* kp = Ks + (kt*16 + col)*72 + quad*8;
        bf16x8 kb0 = *(const bf16x8*)(kp);
        bf16x8 kb1 = *(const bf16x8*)(kp + 32);
        s_acc = __builtin_amdgcn_mfma_f32_16x16x32_bf16(qa[0], kb0, s_acc, 0,0,0);
        s_acc = __builtin_amdgcn_mfma_f32_16x16x32_bf16(qa[1], kb1, s_acc, 0,0,0);
        const int kcol = ((t*16 + col) ^ (quad*8));
        #pragma unroll
        for (int r = 0; r < 4; ++r) {
          uint32_t mw = Ms[wv][(quad*4+r)*16 + c*4 + (kt>>1)];
          float p = ((mw >> ((kt&1)*16 + col)) & 1u)
                      ? exp2f_(fminf(s_acc[r], 43.f)) : 0.f;   // s pre-scaled
          l_part[r] += p;
          Pl[wv][(quad*4+r)*32 + kcol] = (short)f2bf(p);
        }
      }
      bf16x8 pa = *(const bf16x8*)(&Pl[wv][col*32 + ((quad*8) ^ (((col)>>2)*8))]);
      #pragma unroll
      for (int nt = 0; nt < 4; ++nt) {
        bf16x8 vb = *(const bf16x8*)(&Vt[(nt*16+col)*136 + kc*32 + quad*8]);
        o_acc[nt] = __builtin_amdgcn_mfma_f32_16x16x32_bf16(pa, vb, o_acc[nt], 0,0,0);
      }
    }
  }

  float inv[4];
  #pragma unroll
  for (int r = 0; r < 4; ++r) {
    float v = l_part[r];
    v += __shfl_xor(v, 1);
    v += __shfl_xor(v, 2);
    v += __shfl_xor(v, 4);
    v += __shfl_xor(v, 8);
    inv[r] = rcpf_(fmaxf(v, 1e-20f));
  }

  // feat attn-half write (required output)
  #pragma unroll
  for (int nt = 0; nt < 4; ++nt)
    #pragma unroll
    for (int r = 0; r < 4; ++r)
      feat[(size_t)(qbase + quad*4 + r)*128 + 64 + nt*16 + col] = o_acc[nt][r]*inv[r];

  // ---- fused forecast ----
  __syncthreads();   // all waves done reading Ks/Vt before Ks reuse

  // transpose o*inv (C-layout) into wave-private Ks slice (A-layout source)
  #pragma unroll
  for (int nt = 0; nt < 4; ++nt)
    #pragma unroll
    for (int r = 0; r < 4; ++r)
      Ks[(w16 + quad*4 + r)*72 + nt*16 + col] = (short)f2bf(o_acc[nt][r]*inv[r]);

  // A-frags: kc 0..1 from feat v-half (fp32, written by lstm+mlp); kc 2..3 from Ks
  bf16x8 af[4];
  const float* fr = feat + (size_t)(qbase + col)*128;
  #pragma unroll
  for (int kc = 0; kc < 2; ++kc) {
    float4 f0 = *(const float4*)(fr + kc*32 + quad*8);
    float4 f1 = *(const float4*)(fr + kc*32 + quad*8 + 4);
    af[kc][0]=(short)f2bf(f0.x); af[kc][1]=(short)f2bf(f0.y);
    af[kc][2]=(short)f2bf(f0.z); af[kc][3]=(short)f2bf(f0.w);
    af[kc][4]=(short)f2bf(f1.x); af[kc][5]=(short)f2bf(f1.y);
    af[kc][6]=(short)f2bf(f1.z); af[kc][7]=(short)f2bf(f1.w);
  }
  #pragma unroll
  for (int kc = 2; kc < 4; ++kc)
    af[kc] = *(const bf16x8*)(Ks + (w16 + col)*72 + (kc-2)*32 + quad*8);

  f32x4 facc[2];
  #pragma unroll
  for (int nt = 0; nt < 2; ++nt) {
    int n = nt*16 + col;
    float bb = (n < 24) ? bfv[n] : 0.f;
    facc[nt][0] = bb; facc[nt][1] = bb; facc[nt][2] = bb; facc[nt][3] = bb;
  }
  #pragma unroll
  for (int kc = 0; kc < 4; ++kc) {
    #pragma unroll
    for (int nt = 0; nt < 2; ++nt) {
      bf16x8 bfr = *(const bf16x8*)(wg + (size_t)6*4096 + (kc*2+nt)*512 + lane*8);
      facc[nt] = __builtin_amdgcn_mfma_f32_16x16x32_bf16(af[kc], bfr, facc[nt], 0,0,0);
    }
  }

  #pragma unroll
  for (int nt = 0; nt < 2; ++nt) {
    int n = nt*16 + col;
    if (n < 24) {
      #pragma unroll
      for (int r = 0; r < 4; ++r)
        out[(size_t)(qbase + quad*4 + r)*24 + n] = facc[nt][r];
    }
  }
}

// ---------------------------------------------------------------------------
extern "C" void kernel_launch(void* const* d_in, const int* in_sizes, int n_in,
                              void* d_out, int out_size, void* d_ws, size_t ws_size,
                              hipStream_t stream)
{
  const float* obs = (const float*)d_in[0];
  const int*   pm  = (const int*)  d_in[1];
  const float* nhm = (const float*)d_in[2];
  const float* Wih = (const float*)d_in[3];
  const float* Whh = (const float*)d_in[4];
  const float* bih = (const float*)d_in[5];
  const float* bhh = (const float*)d_in[6];
  const float* W1  = (const float*)d_in[7];
  const float* b1  = (const float*)d_in[8];
  const float* W2  = (const float*)d_in[9];
  const float* b2  = (const float*)d_in[10];
  const float* Wh  = (const float*)d_in[11];
  const float* bh  = (const float*)d_in[12];
  const float* Wq  = (const float*)d_in[13];
  const float* bq  = (const float*)d_in[14];
  const float* Wk  = (const float*)d_in[15];
  const float* bk  = (const float*)d_in[16];
  const float* Wv  = (const float*)d_in[17];
  const float* bv  = (const float*)d_in[18];
  const float* Wf  = (const float*)d_in[19];
  const float* bf  = (const float*)d_in[20];

  float* out  = (float*)d_out;                 // forecast: 65536*24
  float* feat = out + (size_t)M_*24;           // feat:     65536*128

  // workspace: qb(8MB) | kb(8MB) | vt(8MB) | bitmask(4MB) | wg(92KB)
  char* ws = (char*)d_ws;
  unsigned short* qbf = (unsigned short*)(ws);
  unsigned short* kbf = (unsigned short*)(ws + (size_t) 8*1024*1024);
  unsigned short* vtb = (unsigned short*)(ws + (size_t)16*1024*1024);
  uint32_t*       bmw = (uint32_t*)      (ws + (size_t)24*1024*1024);
  unsigned short* wgb = (unsigned short*)(ws + (size_t)28*1024*1024);

  wconv_kernel<<<12, 512, 0, stream>>>(W1, W2, Wh, Wq, Wk, Wv, Wf,
                                       Wih, Whh, bih, bhh, wgb);
  lstm_kernel<<<M_/64, 512, 0, stream>>>(obs, nhm, (const int4*)pm, bmw, wgb,
                                         b1, b2, bh, bq, bk, bv,
                                         qbf, kbf, vtb, feat);
  attn_kernel<<<M_/64, 256, 0, stream>>>(qbf, kbf, vtb, bmw, feat, wgb, bf, out);
}

// Round 15
// 295.746 us; speedup vs baseline: 1.1202x; 1.1202x over previous
//
#include <hip/hip_runtime.h>
#include <hip/hip_bf16.h>
#include <stdint.h>

#define B_ 128
#define N_ 512
#define S_ 8
#define H_ 64
#define M_ (B_*N_)          // 65536 rows
#define L2E 1.442695041f

// wg layout (shorts): 7 matrices x 4096 | Whh frags 16384 | Wxc 1024
#define WHH_OFF 28672
#define WXC_OFF 45056

typedef __attribute__((ext_vector_type(8))) short bf16x8;
typedef __attribute__((ext_vector_type(4))) float f32x4;

__device__ __forceinline__ float exp2f_(float x) { return __builtin_amdgcn_exp2f(x); }
__device__ __forceinline__ float rcpf_(float x)  { return __builtin_amdgcn_rcpf(x); }
// x pre-scaled by log2(e):  sig2(x) == sigmoid(x / L2E)   (v_exp + v_rcp only)
__device__ __forceinline__ float sig2(float x)  { return rcpf_(1.f + exp2f_(-x)); }
// x pre-scaled by 2*log2(e): tanh2(x) == tanh(x / (2*L2E))
__device__ __forceinline__ float tanh2(float x) { return 1.f - 2.f*rcpf_(exp2f_(x) + 1.f); }
// fp32 -> bf16 round-to-nearest-even
__device__ __forceinline__ unsigned short f2bf(float x) {
  unsigned int u = __float_as_uint(x);
  u += 0x7fffu + ((u >> 16) & 1u);
  return (unsigned short)(u >> 16);
}

// ---------------------------------------------------------------------------
// One-shot weight conversion, 12 blocks x 512 threads (~4 us):
//  blocks 0..5 : {W1,W2,Wh,Wq,Wk,Wv} bf16 B-frags (Wq pre-scaled by log2(e))
//  block  6    : Wf B-frags, zero-padded to 32 cols
//  blocks 7..10: Whh gate-scaled B-frags
//  block  11   : compact Wxc [Wih0,Wih1,bias,0] per n
__global__ __launch_bounds__(512) void wconv_kernel(
    const float* __restrict__ W1, const float* __restrict__ W2,
    const float* __restrict__ Wh, const float* __restrict__ Wq,
    const float* __restrict__ Wk, const float* __restrict__ Wv,
    const float* __restrict__ Wf, const float* __restrict__ Wih,
    const float* __restrict__ Whh, const float* __restrict__ bih,
    const float* __restrict__ bhh, unsigned short* __restrict__ wg)
{
  const int m = blockIdx.x;
  const int tid = threadIdx.x;
  if (m < 6) {
    const int f = tid >> 6, l = tid & 63;
    const int lq = l >> 4, lc = l & 15;
    const float* mats[6] = {W1, W2, Wh, Wq, Wk, Wv};
    const float sc = (m == 3) ? L2E : 1.f;       // Wq pre-scaled by log2(e)
    const int nt = f >> 1, s = f & 1;
    const float* src = mats[m] + (size_t)(nt*16 + lc)*64 + s*32 + lq*8;
    bf16x8 v;
    #pragma unroll
    for (int j = 0; j < 8; ++j) v[j] = (short)f2bf(src[j] * sc);
    *(bf16x8*)(wg + (size_t)m*4096 + f*512 + l*8) = v;
  } else if (m == 6) {
    const int f = tid >> 6, l = tid & 63;
    const int lq = l >> 4, lc = l & 15;
    const int kc = f >> 1, nt = f & 1;
    const int n = nt*16 + lc;
    bf16x8 v;
    #pragma unroll
    for (int j = 0; j < 8; ++j) v[j] = 0;
    if (n < 24) {
      const float* src = Wf + (size_t)n*128 + kc*32 + lq*8;
      #pragma unroll
      for (int j = 0; j < 8; ++j) v[j] = (short)f2bf(src[j]);
    }
    *(bf16x8*)(wg + (size_t)6*4096 + f*512 + l*8) = v;
  } else if (m < 11) {
    // Whh gate-scaled B-frags
    const int p = (m - 7)*512 + tid;             // 0..2047
    const int f = p >> 6, l = p & 63;
    const int t16 = f >> 1, s = f & 1;
    const int lq = l >> 4, lc = l & 15;
    const float sc = (t16 >= 8 && t16 < 12) ? (2.f*L2E) : L2E;
    const float* src = Whh + (size_t)(t16*16 + lc)*64 + s*32 + lq*8;
    bf16x8 v;
    #pragma unroll
    for (int j = 0; j < 8; ++j) v[j] = (short)f2bf(src[j] * sc);
    *(bf16x8*)(wg + WHH_OFF + (size_t)p*8) = v;
  } else {
    // compact Wx: [t16*64 + cc*4 + k], k: 0=Wih0 1=Wih1 2=bias 3=0
    if (tid < 256) {
      const int t16 = tid >> 4, cc = tid & 15;
      const int n = t16*16 + cc;
      const float sc = (t16 >= 8 && t16 < 12) ? (2.f*L2E) : L2E;
      unsigned short* d = wg + WXC_OFF + t16*64 + cc*4;
      d[0] = f2bf(Wih[2*n + 0] * sc);
      d[1] = f2bf(Wih[2*n + 1] * sc);
      d[2] = f2bf((bih[n] + bhh[n]) * sc);
      d[3] = 0;
    }
  }
}

// ---------------------------------------------------------------------------
// FUSED LSTM+MLP v16 = v14 exactly (R14's wave-pair cc-split REVERTED:
// 8 per-step block barriers + doubled prologue traffic + bank conflicts
// cost more than the occupancy gain — lstm 83 -> 113+. The barrier-free
// per-wave t-loop at 2 blocks/CU is the proven structure at ~83 us).
__global__ __launch_bounds__(512, 4) void lstm_kernel(
    const float* __restrict__ obs, const float* __restrict__ nhm,
    const int4* __restrict__ pm4, uint32_t* __restrict__ bm,
    const unsigned short* __restrict__ wg,
    const float* __restrict__ b1, const float* __restrict__ b2,
    const float* __restrict__ bh, const float* __restrict__ bq,
    const float* __restrict__ bk, const float* __restrict__ bv,
    unsigned short* __restrict__ qb, unsigned short* __restrict__ kb,
    unsigned short* __restrict__ vt, float* __restrict__ feat)
{
  __shared__ short    Wfrag[32*512];   // 32 KB  Whh B-frags (bf16, gate-scaled)
  __shared__ short    Wxc[1024];       // 2 KB   compact [Wih0,Wih1,bias,0] per n
  __shared__ short    h_s[128*72];     // 18 KB  bf16, stride 72 (reused as Atile)

  const int tid  = threadIdx.x;
  const int lane = tid & 63;
  const int wv   = tid >> 6;           // 0..7
  const int w16  = wv * 16;
  const int quad = lane >> 4;
  const int col  = lane & 15;
  const int row0 = blockIdx.x * 128;

  // pm strip for this wave: 256 words = 2048 int4
  const int     wb  = (blockIdx.x*8 + wv) * 256;       // word base
  const int4*   pw  = pm4 + (size_t)wb * 8;            // int4 base
  const int     shp = (lane & 7) * 4;                  // nibble shift

  // ---- prologue: coalesced copies from pre-converted wg ----
  #pragma unroll
  for (int i = 0; i < 4; ++i) {
    int p = i*512 + tid;               // (f*64+l) entry index; dst off = p*8
    *(bf16x8*)(Wfrag + (size_t)p*8) =
        *(const bf16x8*)(wg + WHH_OFF + (size_t)p*8);
  }
  ((uint32_t*)Wxc)[tid] = ((const uint32_t*)(wg + WXC_OFF))[tid];

  // zero h_s (4608 dwords)
  #pragma unroll
  for (int i = 0; i < 9; ++i) ((uint32_t*)h_s)[i*512 + tid] = 0u;

  // ---- per-lane x prep for row (w16+col); all quads redundant, so each
  //      consumer lane already holds its own value. Registers, no LDS.
  uint32_t xq0, xq1, xq2, xq3, xq4, xq5, xq6, xq7;
  int len;
  {
    const int grow = row0 + w16 + col;
    float xv0[8], xv1[8];
    int lzi = -1;
    #pragma unroll
    for (int t = 0; t < 8; ++t) {
      float m = nhm[(size_t)grow*8 + t];
      float a = obs[((size_t)grow*8 + t)*2 + 0] * m;
      float b = obs[((size_t)grow*8 + t)*2 + 1] * m;
      xv0[t] = a; xv1[t] = b;
      if (a == 0.f) lzi = t;
    }
    uint32_t xr[8];
    #pragma unroll
    for (int t = 0; t < 8; ++t) {
      bool kill = (t < lzi);
      float a = kill ? 0.f : xv0[t];
      float b = kill ? 0.f : xv1[t];
      xr[t] = (uint32_t)f2bf(a) | ((uint32_t)f2bf(b) << 16);
    }
    xq0 = xr[0]; xq1 = xr[1]; xq2 = xr[2]; xq3 = xr[3];
    xq4 = xr[4]; xq5 = xr[5]; xq6 = xr[6]; xq7 = xr[7];
    len = 7 - lzi; if (len < 1) len = 1;
  }
  int lenr[4];
  #pragma unroll
  for (int r = 0; r < 4; ++r) lenr[r] = __shfl(len, quad*4 + r);

  __syncthreads();     // the ONLY barrier (covers Wfrag, Wxc, h_s zero)

  float c_[16];
  #pragma unroll
  for (int i = 0; i < 16; ++i) c_[i] = 0.f;

  const f32x4 zero4 = {0.f, 0.f, 0.f, 0.f};
  const bool q0 = (quad == 0);

  #pragma unroll 1
  for (int t = 0; t < 8; ++t) {
    // ---- ISSUE pm loads for this step early (consumed after cc-loop) ----
    const int4* ps = pw + t*256 + lane;
    int4 pv0 = ps[0];
    int4 pv1 = ps[64];
    int4 pv2 = ps[128];
    int4 pv3 = ps[192];
    __builtin_amdgcn_sched_barrier(0);   // loads stay issued before MFMA region

    // ---- A-frag for the x/bias MFMA: [x0, x1, 1, 0...] on quad 0 ----
    uint32_t xw = xq0;
    // rotate queue (static indices; stays in registers)
    xq0 = xq1; xq1 = xq2; xq2 = xq3; xq3 = xq4;
    xq4 = xq5; xq5 = xq6; xq6 = xq7;

    union { bf16x8 v; uint32_t u[4]; } ax;
    ax.u[0] = q0 ? xw : 0u;
    ax.u[1] = q0 ? 0x00003f80u : 0u;    // bf16(1.0) at k==2
    ax.u[2] = 0u; ax.u[3] = 0u;

    // A-frags of h (bf16, no converts)
    bf16x8 a0 = *(const bf16x8*)(h_s + (w16 + col)*72 + quad*8);
    bf16x8 a1 = *(const bf16x8*)(h_s + (w16 + col)*72 + 32 + quad*8);

    // 4 column-groups: tiles {cc, cc+4, cc+8, cc+12} = i,f,g,o for cells
    // n = cc*16+col. Only 4 accumulators live at a time.
    #pragma unroll
    for (int cc = 0; cc < 4; ++cc) {
      f32x4 acc[4];
      #pragma unroll
      for (int g = 0; g < 4; ++g) {
        const int t16 = g*4 + cc;
        union { bf16x8 v; uint32_t u[4]; } wx;
        uint2 d = *(const uint2*)(Wxc + t16*64 + col*4);  // always initialized
        wx.u[0] = q0 ? d.x : 0u;        // zero fragment on non-quad0 lanes
        wx.u[1] = q0 ? d.y : 0u;
        wx.u[2] = 0u; wx.u[3] = 0u;
        bf16x8 b0 = *(const bf16x8*)(Wfrag + (t16*2+0)*512 + lane*8);
        bf16x8 b1 = *(const bf16x8*)(Wfrag + (t16*2+1)*512 + lane*8);
        acc[g] = __builtin_amdgcn_mfma_f32_16x16x32_bf16(ax.v, wx.v, zero4, 0, 0, 0);
        acc[g] = __builtin_amdgcn_mfma_f32_16x16x32_bf16(a0, b0, acc[g], 0, 0, 0);
        acc[g] = __builtin_amdgcn_mfma_f32_16x16x32_bf16(a1, b1, acc[g], 0, 0, 0);
      }
      #pragma unroll
      for (int r = 0; r < 4; ++r) {
        if (t < lenr[r]) {
          float gi = acc[0][r];
          float gf = acc[1][r];
          float gg = acc[2][r];
          float go = acc[3][r];
          float cn = sig2(gf)*c_[cc*4+r] + sig2(gi)*tanh2(gg);
          c_[cc*4+r] = cn;
          h_s[(w16 + quad*4 + r)*72 + cc*16 + col] =
              (short)f2bf(sig2(go)*tanh2(cn*(2.f*L2E)));
        }
      }
      __builtin_amdgcn_sched_barrier(0);  // pin group: keep acc lifetime short
    }

    // ---- CONSUME pm loads (latency hidden under the cc-loop above) ----
    {
      int4 vv[4] = {pv0, pv1, pv2, pv3};
      #pragma unroll
      for (int jj = 0; jj < 4; ++jj) {
        int4 v = vv[jj];
        uint32_t nib = (v.x != 0 ? 1u : 0u)
                     | (v.y != 0 ? 2u : 0u)
                     | (v.z != 0 ? 4u : 0u)
                     | (v.w != 0 ? 8u : 0u);
        uint32_t x = nib << shp;
        x |= __shfl_xor(x, 1);
        x |= __shfl_xor(x, 2);
        x |= __shfl_xor(x, 4);
        if ((lane & 7) == 0)
          bm[wb + t*32 + jj*8 + (lane >> 3)] = x;
      }
      __builtin_amdgcn_sched_barrier(0);  // keep pm block out of next step's MFMA region
    }
    // no per-step barrier: each wave owns its 16 h rows
  }

  // ======================= fused MLP epilogue (per-wave) ====================
  // A-frags = relu(h) of this wave's own rows (same bits as old he path).
  short* At = h_s + w16*72;            // this wave's 16-row slice, stride 72
  const int grow16 = row0 + w16;       // row base for this wave

  auto reluv = [](bf16x8 v) {
    #pragma unroll
    for (int j = 0; j < 8; ++j) {
      short sv = v[j];
      v[j] = (sv & (short)0x8000) ? (short)0 : sv;
    }
    return v;
  };

  bf16x8 a0 = reluv(*(const bf16x8*)(At + col*72 + quad*8));
  bf16x8 a1 = reluv(*(const bf16x8*)(At + col*72 + 32 + quad*8));

  f32x4 acc[4];
  auto runL = [&](int m, const float* __restrict__ bs, float bsc) {
    bf16x8 bf[8];
    #pragma unroll
    for (int f = 0; f < 8; ++f)
      bf[f] = *(const bf16x8*)(wg + (size_t)m*4096 + f*512 + lane*8);
    #pragma unroll
    for (int nt = 0; nt < 4; ++nt) {
      float bb = bs[nt*16 + col] * bsc;
      acc[nt][0] = bb; acc[nt][1] = bb; acc[nt][2] = bb; acc[nt][3] = bb;
      acc[nt] = __builtin_amdgcn_mfma_f32_16x16x32_bf16(a0, bf[nt*2+0], acc[nt], 0,0,0);
      acc[nt] = __builtin_amdgcn_mfma_f32_16x16x32_bf16(a1, bf[nt*2+1], acc[nt], 0,0,0);
    }
  };
  auto tileWrite = [&](bool relu) {
    #pragma unroll
    for (int nt = 0; nt < 4; ++nt)
      #pragma unroll
      for (int r = 0; r < 4; ++r) {
        float v = relu ? fmaxf(acc[nt][r], 0.f) : acc[nt][r];
        At[(quad*4+r)*72 + ((nt*16+col) ^ (r*16))] = (short)f2bf(v);
      }
  };
  auto tileReadA = [&]() {
    int sw = (col & 3) * 16;
    a0 = *(const bf16x8*)(At + col*72 + ((quad*8     ) ^ sw));
    a1 = *(const bf16x8*)(At + col*72 + ((quad*8 + 32) ^ sw));
  };
  auto storeBF = [&](unsigned short* dst) {
    #pragma unroll
    for (int s = 0; s < 2; ++s) {
      int chunk = s*64 + lane;
      int r = chunk >> 3, c8 = chunk & 7;
      bf16x8 v = *(const bf16x8*)(At + r*72 + ((c8*8) ^ ((r&3)*16)));
      *(bf16x8*)(dst + (size_t)(grow16 + r)*64 + c8*8) = v;
    }
  };

  runL(0, b1, 1.f);  tileWrite(true);  tileReadA();
  runL(1, b2, 1.f);  tileWrite(true);  tileReadA();
  runL(2, bh, 1.f);  tileWrite(true);  tileReadA();   // a0/a1 = hidden A-frags
  runL(3, bq, L2E);  tileWrite(false); storeBF(qb);   // q (bf16, L2E-scaled)
  runL(4, bk, 1.f);  tileWrite(false); storeBF(kb);   // k (bf16)
  runL(5, bv, 1.f);                                   // v
  {
    const int bi   = grow16 >> 9;                // batch
    const int key0 = (grow16 & 511) + quad*4;
    #pragma unroll
    for (int nt = 0; nt < 4; ++nt) {
      #pragma unroll
      for (int r = 0; r < 4; ++r)
        feat[(size_t)(grow16 + quad*4 + r)*128 + nt*16 + col] = acc[nt][r];
      uint32_t lo = (uint32_t)f2bf(acc[nt][0]) | ((uint32_t)f2bf(acc[nt][1]) << 16);
      uint32_t hi = (uint32_t)f2bf(acc[nt][2]) | ((uint32_t)f2bf(acc[nt][3]) << 16);
      uint2 pk; pk.x = lo; pk.y = hi;
      *(uint2*)(vt + ((size_t)bi*64 + nt*16 + col)*512 + key0) = pk;
    }
  }
}

// ---------------------------------------------------------------------------
// MFMA attention v4 (unchanged): fused forecast epilogue, Wf frags from wg.
__global__ __launch_bounds__(256) void attn_kernel(
    const unsigned short* __restrict__ qg, const unsigned short* __restrict__ kg,
    const unsigned short* __restrict__ vt,
    const uint32_t* __restrict__ bm, float* __restrict__ feat,
    const unsigned short* __restrict__ wg, const float* __restrict__ bfv,
    float* __restrict__ out)
{
  __shared__ short    Ks[128*72];      // 18.0 KB (reused as o-tile in epilogue)
  __shared__ short    Vt[64*136];      // 17.0 KB
  __shared__ short    Pl[4][16*32];    // 4 KB, per-wave
  __shared__ uint32_t Ms[4][256];      // 4 KB, per-wave mask words

  const int tid  = threadIdx.x;
  const int lane = tid & 63;
  const int wv   = tid >> 6;
  const int w16  = wv * 16;
  const int quad = lane >> 4;
  const int col  = lane & 15;

  const int b     = blockIdx.x >> 3;
  const int q0    = (blockIdx.x & 7) * 64;
  const int qbase = b*512 + q0 + wv*16;

  bf16x8 qa[2];
  qa[0] = *(const bf16x8*)(qg + (size_t)(qbase + col)*64 + quad*8);
  qa[1] = *(const bf16x8*)(qg + (size_t)(qbase + col)*64 + quad*8 + 32);

  #pragma unroll
  for (int w = 0; w < 4; ++w)
    Ms[wv][w*64 + lane] = bm[(size_t)qbase*16 + w*64 + lane];

  f32x4 o_acc[4];
  #pragma unroll
  for (int nt = 0; nt < 4; ++nt)
    #pragma unroll
    for (int r = 0; r < 4; ++r) o_acc[nt][r] = 0.f;
  float l_part[4] = {0.f, 0.f, 0.f, 0.f};

  const unsigned short* vtb = vt + (size_t)b*64*512;

  for (int c = 0; c < 4; ++c) {
    __syncthreads();
    {
      const int kb_ = b*512 + c*128;
      // K chunk: bf16 [key][dim] stride 72
      #pragma unroll
      for (int i = 0; i < 4; ++i) {
        int p = i*256 + tid;
        int key = p >> 3, c8 = p & 7;
        bf16x8 kv = *(const bf16x8*)(kg + (size_t)(kb_ + key)*64 + c8*8);
        *(bf16x8*)(Ks + key*72 + c8*8) = kv;
      }
      // V^T chunk: bf16 [dim][key] stride 136 — pure copies
      #pragma unroll
      for (int i = 0; i < 4; ++i) {
        int p = i*256 + tid;
        int dim = p >> 4, k8 = p & 15;
        bf16x8 vv = *(const bf16x8*)(vtb + (size_t)dim*512 + c*128 + k8*8);
        *(bf16x8*)(Vt + dim*136 + k8*8) = vv;
      }
    }
    __syncthreads();

    for (int kc = 0; kc < 4; ++kc) {
      #pragma unroll
      for (int t = 0; t < 2; ++t) {
        const int kt = kc*2 + t;
        f32x4 s_acc;
        #pragma unroll
        for (int r = 0; r < 4; ++r) s_acc[r] = 0.f;
        const short* kp = Ks + (kt*16 + col)*72 + quad*8;
        bf16x8 kb0 = *(const bf16x8*)(kp);
        bf16x8 kb1 = *(const bf16x8*)(kp + 32);
        s_acc = __builtin_amdgcn_mfma_f32_16x16x32_bf16(qa[0], kb0, s_acc, 0,0,0);
        s_acc = __builtin_amdgcn_mfma_f32_16x16x32_bf16(qa[1], kb1, s_acc, 0,0,0);
        const int kcol = ((t*16 + col) ^ (quad*8));
        #pragma unroll
        for (int r = 0; r < 4; ++r) {
          uint32_t mw = Ms[wv][(quad*4+r)*16 + c*4 + (kt>>1)];
          float p = ((mw >> ((kt&1)*16 + col)) & 1u)
                      ? exp2f_(fminf(s_acc[r], 43.f)) : 0.f;   // s pre-scaled
          l_part[r] += p;
          Pl[wv][(quad*4+r)*32 + kcol] = (short)f2bf(p);
        }
      }
      bf16x8 pa = *(const bf16x8*)(&Pl[wv][col*32 + ((quad*8) ^ (((col)>>2)*8))]);
      #pragma unroll
      for (int nt = 0; nt < 4; ++nt) {
        bf16x8 vb = *(const bf16x8*)(&Vt[(nt*16+col)*136 + kc*32 + quad*8]);
        o_acc[nt] = __builtin_amdgcn_mfma_f32_16x16x32_bf16(pa, vb, o_acc[nt], 0,0,0);
      }
    }
  }

  float inv[4];
  #pragma unroll
  for (int r = 0; r < 4; ++r) {
    float v = l_part[r];
    v += __shfl_xor(v, 1);
    v += __shfl_xor(v, 2);
    v += __shfl_xor(v, 4);
    v += __shfl_xor(v, 8);
    inv[r] = rcpf_(fmaxf(v, 1e-20f));
  }

  // feat attn-half write (required output)
  #pragma unroll
  for (int nt = 0; nt < 4; ++nt)
    #pragma unroll
    for (int r = 0; r < 4; ++r)
      feat[(size_t)(qbase + quad*4 + r)*128 + 64 + nt*16 + col] = o_acc[nt][r]*inv[r];

  // ---- fused forecast ----
  __syncthreads();   // all waves done reading Ks/Vt before Ks reuse

  // transpose o*inv (C-layout) into wave-private Ks slice (A-layout source)
  #pragma unroll
  for (int nt = 0; nt < 4; ++nt)
    #pragma unroll
    for (int r = 0; r < 4; ++r)
      Ks[(w16 + quad*4 + r)*72 + nt*16 + col] = (short)f2bf(o_acc[nt][r]*inv[r]);

  // A-frags: kc 0..1 from feat v-half (fp32, written by lstm+mlp); kc 2..3 from Ks
  bf16x8 af[4];
  const float* fr = feat + (size_t)(qbase + col)*128;
  #pragma unroll
  for (int kc = 0; kc < 2; ++kc) {
    float4 f0 = *(const float4*)(fr + kc*32 + quad*8);
    float4 f1 = *(const float4*)(fr + kc*32 + quad*8 + 4);
    af[kc][0]=(short)f2bf(f0.x); af[kc][1]=(short)f2bf(f0.y);
    af[kc][2]=(short)f2bf(f0.z); af[kc][3]=(short)f2bf(f0.w);
    af[kc][4]=(short)f2bf(f1.x); af[kc][5]=(short)f2bf(f1.y);
    af[kc][6]=(short)f2bf(f1.z); af[kc][7]=(short)f2bf(f1.w);
  }
  #pragma unroll
  for (int kc = 2; kc < 4; ++kc)
    af[kc] = *(const bf16x8*)(Ks + (w16 + col)*72 + (kc-2)*32 + quad*8);

  f32x4 facc[2];
  #pragma unroll
  for (int nt = 0; nt < 2; ++nt) {
    int n = nt*16 + col;
    float bb = (n < 24) ? bfv[n] : 0.f;
    facc[nt][0] = bb; facc[nt][1] = bb; facc[nt][2] = bb; facc[nt][3] = bb;
  }
  #pragma unroll
  for (int kc = 0; kc < 4; ++kc) {
    #pragma unroll
    for (int nt = 0; nt < 2; ++nt) {
      bf16x8 bfr = *(const bf16x8*)(wg + (size_t)6*4096 + (kc*2+nt)*512 + lane*8);
      facc[nt] = __builtin_amdgcn_mfma_f32_16x16x32_bf16(af[kc], bfr, facc[nt], 0,0,0);
    }
  }

  #pragma unroll
  for (int nt = 0; nt < 2; ++nt) {
    int n = nt*16 + col;
    if (n < 24) {
      #pragma unroll
      for (int r = 0; r < 4; ++r)
        out[(size_t)(qbase + quad*4 + r)*24 + n] = facc[nt][r];
    }
  }
}

// ---------------------------------------------------------------------------
extern "C" void kernel_launch(void* const* d_in, const int* in_sizes, int n_in,
                              void* d_out, int out_size, void* d_ws, size_t ws_size,
                              hipStream_t stream)
{
  const float* obs = (const float*)d_in[0];
  const int*   pm  = (const int*)  d_in[1];
  const float* nhm = (const float*)d_in[2];
  const float* Wih = (const float*)d_in[3];
  const float* Whh = (const float*)d_in[4];
  const float* bih = (const float*)d_in[5];
  const float* bhh = (const float*)d_in[6];
  const float* W1  = (const float*)d_in[7];
  const float* b1  = (const float*)d_in[8];
  const float* W2  = (const float*)d_in[9];
  const float* b2  = (const float*)d_in[10];
  const float* Wh  = (const float*)d_in[11];
  const float* bh  = (const float*)d_in[12];
  const float* Wq  = (const float*)d_in[13];
  const float* bq  = (const float*)d_in[14];
  const float* Wk  = (const float*)d_in[15];
  const float* bk  = (const float*)d_in[16];
  const float* Wv  = (const float*)d_in[17];
  const float* bv  = (const float*)d_in[18];
  const float* Wf  = (const float*)d_in[19];
  const float* bf  = (const float*)d_in[20];

  float* out  = (float*)d_out;                 // forecast: 65536*24
  float* feat = out + (size_t)M_*24;           // feat:     65536*128

  // workspace: qb(8MB) | kb(8MB) | vt(8MB) | bitmask(4MB) | wg(92KB)
  char* ws = (char*)d_ws;
  unsigned short* qbf = (unsigned short*)(ws);
  unsigned short* kbf = (unsigned short*)(ws + (size_t) 8*1024*1024);
  unsigned short* vtb = (unsigned short*)(ws + (size_t)16*1024*1024);
  uint32_t*       bmw = (uint32_t*)      (ws + (size_t)24*1024*1024);
  unsigned short* wgb = (unsigned short*)(ws + (size_t)28*1024*1024);

  wconv_kernel<<<12, 512, 0, stream>>>(W1, W2, Wh, Wq, Wk, Wv, Wf,
                                       Wih, Whh, bih, bhh, wgb);
  lstm_kernel<<<M_/128, 512, 0, stream>>>(obs, nhm, (const int4*)pm, bmw, wgb,
                                          b1, b2, bh, bq, bk, bv,
                                          qbf, kbf, vtb, feat);
  attn_kernel<<<M_/64, 256, 0, stream>>>(qbf, kbf, vtb, bmw, feat, wgb, bf, out);
}